// Round 7
// baseline (166.619 us; speedup 1.0000x reference)
//
#include <hip/hip_runtime.h>
#include <stdint.h>

#define BATCH 8
#define SEQ   2048
#define DIM   512

typedef __attribute__((ext_vector_type(8)))  short short8;    // 8 bf16 (4 VGPRs)
typedef __attribute__((ext_vector_type(16))) float floatx16;  // 32x32 C/D frag

static __device__ __forceinline__ unsigned short f32_bf16(float f) {
  unsigned u = __builtin_bit_cast(unsigned, f);
  u += 0x7FFFu + ((u >> 16) & 1u);          // round-to-nearest-even
  return (unsigned short)(u >> 16);
}
static __device__ __forceinline__ short8 ld_frag8(const unsigned short* p) {
  return __builtin_bit_cast(short8, *reinterpret_cast<const uint4*>(p));
}
static __device__ __forceinline__ void gld_lds16(const unsigned short* g, unsigned short* l) {
  __builtin_amdgcn_global_load_lds((const __attribute__((address_space(1))) unsigned int*)g,
                                   (__attribute__((address_space(3))) unsigned int*)l, 16, 0, 0);
}
static __device__ __forceinline__ float bf_lo(unsigned u) {
  return __builtin_bit_cast(float, u << 16);
}
static __device__ __forceinline__ float bf_hi(unsigned u) {
  return __builtin_bit_cast(float, u & 0xFFFF0000u);
}
static __device__ __forceinline__ float bfu(unsigned short u) {
  return __builtin_bit_cast(float, (unsigned)u << 16);
}
static __device__ __forceinline__ void wait_vm_barrier_4() {
  asm volatile("s_waitcnt vmcnt(4)" ::: "memory");   // stage(kc+1) landed; kc+2 in flight
  __builtin_amdgcn_s_barrier();
  __builtin_amdgcn_sched_barrier(0);
}
static __device__ __forceinline__ void wait_vm_barrier_0() {
  asm volatile("s_waitcnt vmcnt(0)" ::: "memory");
  __builtin_amdgcn_s_barrier();
  __builtin_amdgcn_sched_barrier(0);
}

// ---------------- prep: x -> xn (bf16 x-hat, row-major) and xt (bf16 x^T, BLOCKED) ---------
// xt layout: [b][jt][d][j&31]  (jt = j>>5) -> each block owns ONE contiguous 32KB chunk.
// grid 512 = 8 batches (XCD-pinned &7) x 64 j-tiles of 32 rows ; 256 threads
__global__ __launch_bounds__(256) void prep_kernel(const float* __restrict__ x,
                                                   unsigned short* __restrict__ xn,
                                                   unsigned short* __restrict__ xt) {
  const int b   = blockIdx.x & 7;
  const int jt  = blockIdx.x >> 3;     // 0..63
  const int t   = threadIdx.x;
  const int row = t >> 3;              // 0..31
  const int oct = t & 7;               // 0..7

  __shared__ unsigned short xs[512 * 34];   // [d][j] bf16, pitch 34 u16 (34.8 KB)

  const long rowg = ((long)b * SEQ + jt * 32 + row) * DIM;
  const float* xp = x + rowg;

  float4 v[16];
#pragma unroll
  for (int k = 0; k < 16; ++k)
    v[k] = *reinterpret_cast<const float4*>(xp + k * 32 + oct * 4);

  float acc = 0.f;
#pragma unroll
  for (int k = 0; k < 16; ++k)
    acc += v[k].x*v[k].x + v[k].y*v[k].y + v[k].z*v[k].z + v[k].w*v[k].w;
  acc += __shfl_xor(acc, 1);
  acc += __shfl_xor(acc, 2);
  acc += __shfl_xor(acc, 4);
  const float sc = 1.f / (sqrtf(acc) + 1e-12f);

  // xn straight from registers
  unsigned short* xnp = xn + rowg + oct * 4;
#pragma unroll
  for (int k = 0; k < 16; ++k) {
    ushort4 pk;
    pk.x = f32_bf16(v[k].x * sc); pk.y = f32_bf16(v[k].y * sc);
    pk.z = f32_bf16(v[k].z * sc); pk.w = f32_bf16(v[k].w * sc);
    *reinterpret_cast<ushort4*>(xnp + k * 32) = pk;
  }

  // LDS transpose staging: scalar u16 writes, bank = 4*oct + row/2 + const -> free
#pragma unroll
  for (int k = 0; k < 16; ++k) {
    const int d = k * 32 + oct * 4;
    xs[(d + 0) * 34 + row] = f32_bf16(v[k].x);
    xs[(d + 1) * 34 + row] = f32_bf16(v[k].y);
    xs[(d + 2) * 34 + row] = f32_bf16(v[k].z);
    xs[(d + 3) * 34 + row] = f32_bf16(v[k].w);
  }
  __syncthreads();

  // xt chunk store: contiguous 32KB, fully coalesced.
  unsigned short* xtb = xt + (size_t)(b * 64 + jt) * (512 * 32);
#pragma unroll
  for (int it = 0; it < 8; ++it) {
    const int a = t >> 2;                      // 0..63 d-sub
    const int q = (t & 3) ^ ((t >> 4) & 3);    // read/store group 0..3
    const int d = it * 64 + a;
    const unsigned* bp = reinterpret_cast<const unsigned*>(&xs[d * 34 + q * 8]);
    uint4 o;
    o.x = bp[0]; o.y = bp[1]; o.z = bp[2]; o.w = bp[3];
    *reinterpret_cast<uint4*>(xtb + d * 32 + q * 8) = o;
  }
}

// ---------------- gemm1 (symmetric, 3-stage counted-vmcnt): P = bf16(exp(S^2-1)) ----------
// Upper-triangle tiles (grid 8 x 136). BK=32, 3 LDS slots of 16KB (48KB -> 3 blk/CU).
// Loop: stage(kc+2) -> compute(kc) -> vmcnt(4) [stage(kc+1) landed, kc+2 in flight] ->
// s_barrier. Waits target loads issued TWO compute-phases ago. Tail peels to vmcnt(0).
// r6 BUGFIX: slot rotation was (cur+2==3)?...:cur+2 which yields slot 4 at cur==2 ->
// OOB LDS write + chunk-1 reused for chunk-4. Now explicit (cur+2)%3.
__global__ __launch_bounds__(256, 3) void gemm1_kernel(const unsigned short* __restrict__ xn,
                                                       unsigned short* __restrict__ P,
                                                       float* __restrict__ lw) {
  const int b   = blockIdx.x & 7;
  int idx = blockIdx.x >> 3;           // 0..135 -> (ti, tj), ti <= tj
  int ti = 0;
#pragma unroll 1
  while (idx >= 16 - ti) { idx -= 16 - ti; ++ti; }
  const int tj = ti + idx;
  const int i0 = ti * 128;
  const int j0 = tj * 128;

  const int tid  = threadIdx.x;
  const int w    = tid >> 6;
  const int lane = tid & 63;
  const int ln   = lane & 31;
  const int half = lane >> 5;

  // 3 slots x (A 4096 u16 + B 4096 u16) = 24576 u16 = 48 KB. sP (17408 u16) aliases slot 0+.
  __shared__ __align__(16) unsigned short smem[24576];

  const unsigned short* xb = xn + (long)b * SEQ * DIM;
  const unsigned short* Ag = xb + (long)i0 * DIM;
  const unsigned short* Bg = xb + (long)j0 * DIM;

  floatx16 acc[2][2];
#pragma unroll
  for (int mt = 0; mt < 2; ++mt)
#pragma unroll
    for (int nt = 0; nt < 2; ++nt)
#pragma unroll
      for (int i = 0; i < 16; ++i) acc[mt][nt][i] = 0.f;

  const int r0 = (w >> 1) * 64;
  const int c0 = (w & 1) * 64;

  // stage slot s with K-chunk kc (BK=32): 2 A-granule loads + 2 B-granule loads per thread
  auto stage = [&](int kc, int s) {
    unsigned short* bA = smem + s * 8192;
    unsigned short* bB = bA + 4096;
    const int ko = kc * 32;
#pragma unroll
    for (int k = 0; k < 2; ++k) {
      int u = tid + k * 256;
      int row = u >> 2, c = u & 3;
      int gc = (c ^ ((row >> 1) & 3)) * 8;     // BK=32 conflict-free swizzle key
      gld_lds16(Ag + (long)row * DIM + ko + gc, bA + u * 8);
      gld_lds16(Bg + (long)row * DIM + ko + gc, bB + u * 8);
    }
  };

  // prologue: fill slots 0,1
  stage(0, 0);
  stage(1, 1);
  wait_vm_barrier_4();

  int cur = 0;
  for (int kc = 0; kc < 16; ++kc) {
    if (kc + 2 < 16) {
      int snx = cur + 2; if (snx >= 3) snx -= 3;
      stage(kc + 2, snx);
      __builtin_amdgcn_sched_barrier(0);
    }
    unsigned short* cA = smem + cur * 8192;
    unsigned short* cB = cA + 4096;
#pragma unroll
    for (int kk = 0; kk < 2; ++kk) {
      const int cc = kk * 2 + half;
      short8 af[2], bfr[2];
#pragma unroll
      for (int mt = 0; mt < 2; ++mt) {
        int r = r0 + mt * 32 + ln;
        af[mt] = ld_frag8(cA + r * 32 + ((cc ^ ((r >> 1) & 3)) * 8));
      }
#pragma unroll
      for (int nt = 0; nt < 2; ++nt) {
        int r = c0 + nt * 32 + ln;
        bfr[nt] = ld_frag8(cB + r * 32 + ((cc ^ ((r >> 1) & 3)) * 8));
      }
#pragma unroll
      for (int mt = 0; mt < 2; ++mt)
#pragma unroll
        for (int nt = 0; nt < 2; ++nt)
          acc[mt][nt] = __builtin_amdgcn_mfma_f32_32x32x16_bf16(af[mt], bfr[nt], acc[mt][nt], 0, 0, 0);
    }
    if (kc + 2 < 16) wait_vm_barrier_4();
    else             wait_vm_barrier_0();
    cur = (cur + 1 == 3) ? 0 : cur + 1;
  }

  // epilogue: p = bf16(exp(s^2-1)) once into registers; feed sP, mirror, sums
  unsigned short pb[2][2][16];
  unsigned short* sP = smem;
#pragma unroll
  for (int mt = 0; mt < 2; ++mt)
#pragma unroll
    for (int nt = 0; nt < 2; ++nt) {
      const int col = c0 + nt * 32 + ln;
#pragma unroll
      for (int r = 0; r < 16; ++r) {
        float s = acc[mt][nt][r];
        unsigned short pv = f32_bf16(__expf(__builtin_fmaf(s, s, -1.0f)));
        pb[mt][nt][r] = pv;
        int row = r0 + mt * 32 + (r & 3) + 8 * (r >> 2) + 4 * half;
        sP[row * 136 + col] = pv;
      }
    }
  __syncthreads();

  unsigned short* Pg = P + (long)b * SEQ * SEQ;
  float* lwi = lw + b * SEQ + i0;
  float* lwj = lw + b * SEQ + j0;

  // tile (ti,tj): coalesced stores + fused row-sums
#pragma unroll
  for (int k = 0; k < 8; ++k) {
    int u = tid + k * 256;
    int row = u >> 4, c16 = u & 15;
    uint4 o = *reinterpret_cast<const uint4*>(sP + row * 136 + c16 * 8);
    *reinterpret_cast<uint4*>(Pg + (long)(i0 + row) * SEQ + j0 + c16 * 8) = o;
    float s = bf_lo(o.x) + bf_hi(o.x) + bf_lo(o.y) + bf_hi(o.y)
            + bf_lo(o.z) + bf_hi(o.z) + bf_lo(o.w) + bf_hi(o.w);
    s += __shfl_xor(s, 1);
    s += __shfl_xor(s, 2);
    s += __shfl_xor(s, 4);
    s += __shfl_xor(s, 8);
    if ((tid & 15) == 0) atomicAdd(&lwi[row], s);
  }

  if (ti != tj) {
    // column sums (= row sums of the mirror tile) from the exact bf16 register values
#pragma unroll
    for (int nt = 0; nt < 2; ++nt) {
      const int c = c0 + nt * 32 + ln;
      float s = 0.f;
#pragma unroll
      for (int mt = 0; mt < 2; ++mt)
#pragma unroll
        for (int r = 0; r < 16; ++r) s += bfu(pb[mt][nt][r]);
      s += __shfl_xor(s, 32);           // combine the two row-halves of this wave
      if (half == 0) atomicAdd(&lwj[c], s);
    }
    __syncthreads();                    // direct-tile reads of sP complete
    // rewrite sP TRANSPOSED (sP[c][i]) from registers, then store coalesced full lines
#pragma unroll
    for (int nt = 0; nt < 2; ++nt) {
      const int c = c0 + nt * 32 + ln;
#pragma unroll
      for (int mt = 0; mt < 2; ++mt)
#pragma unroll
        for (int r = 0; r < 16; ++r) {
          const int row = r0 + mt * 32 + (r & 3) + 8 * (r >> 2) + 4 * half;
          sP[c * 136 + row] = pb[mt][nt][r];
        }
    }
    __syncthreads();
#pragma unroll
    for (int k = 0; k < 8; ++k) {
      int u = tid + k * 256;
      int row = u >> 4, c16 = u & 15;   // row = mirror row (j-col), c16 over i
      uint4 o = *reinterpret_cast<const uint4*>(sP + row * 136 + c16 * 8);
      *reinterpret_cast<uint4*>(Pg + (long)(j0 + row) * SEQ + i0 + c16 * 8) = o;
    }
  }
}

// ---------------- gemm2 (3-stage counted-vmcnt): out[b,i,d] = (P . x) / l ----------------
// grid 512 = 8 batches x 16 i x 4 d ; d-FAST ordering ; blocked-xt (chunk index == kc).
// Same BK=32 / 3-slot / vmcnt(4) pipeline; 48KB LDS -> 3 blk/CU.
__global__ __launch_bounds__(256, 3) void gemm2_kernel(const unsigned short* __restrict__ P,
                                                       const unsigned short* __restrict__ xt,
                                                       const float* __restrict__ lw,
                                                       float* __restrict__ out) {
  const int b  = blockIdx.x & 7;
  const int t  = blockIdx.x >> 3;
  const int i0 = (t >> 2) * 128;       // d-fast: i0 slow
  const int n0 = (t & 3) * 128;        // d-fast: n0 fast
  const int tid  = threadIdx.x;
  const int w    = tid >> 6;
  const int lane = tid & 63;
  const int ln   = lane & 31;
  const int half = lane >> 5;

  __shared__ __align__(16) unsigned short smem[24576];   // 48 KB, 3 slots
  __shared__ float sl[128];

  const unsigned short* Ag = P  + (long)b * SEQ * SEQ + (long)i0 * SEQ;
  const unsigned short* Bg = xt + (size_t)b * DIM * SEQ;   // blocked chunks base

  if (tid < 128) sl[tid] = lw[b * SEQ + i0 + tid];

  floatx16 acc[2][2];
#pragma unroll
  for (int mt = 0; mt < 2; ++mt)
#pragma unroll
    for (int nt = 0; nt < 2; ++nt)
#pragma unroll
      for (int i = 0; i < 16; ++i) acc[mt][nt][i] = 0.f;

  const int r0 = (w >> 1) * 64;
  const int c0 = (w & 1) * 64;

  auto stage = [&](int kc, int s) {
    unsigned short* bA = smem + s * 8192;
    unsigned short* bB = bA + 4096;
#pragma unroll
    for (int k = 0; k < 2; ++k) {
      int u = tid + k * 256;
      int row = u >> 2, c = u & 3;
      int gc = (c ^ ((row >> 1) & 3)) * 8;     // BK=32 swizzle key
      gld_lds16(Ag + (long)row * SEQ + kc * 32 + gc, bA + u * 8);
      gld_lds16(Bg + ((size_t)kc * 512 + n0 + row) * 32 + gc, bB + u * 8);
    }
  };

  stage(0, 0);
  stage(1, 1);
  wait_vm_barrier_4();

  int cur = 0;
  for (int kc = 0; kc < 64; ++kc) {
    if (kc + 2 < 64) {
      int snx = cur + 2; if (snx >= 3) snx -= 3;
      stage(kc + 2, snx);
      __builtin_amdgcn_sched_barrier(0);
    }
    unsigned short* cA = smem + cur * 8192;
    unsigned short* cB = cA + 4096;
#pragma unroll
    for (int kk = 0; kk < 2; ++kk) {
      const int cc = kk * 2 + half;
      short8 af[2], bfr[2];
#pragma unroll
      for (int mt = 0; mt < 2; ++mt) {
        int r = r0 + mt * 32 + ln;
        af[mt] = ld_frag8(cA + r * 32 + ((cc ^ ((r >> 1) & 3)) * 8));
      }
#pragma unroll
      for (int nt = 0; nt < 2; ++nt) {
        int r = c0 + nt * 32 + ln;
        bfr[nt] = ld_frag8(cB + r * 32 + ((cc ^ ((r >> 1) & 3)) * 8));
      }
#pragma unroll
      for (int mt = 0; mt < 2; ++mt)
#pragma unroll
        for (int nt = 0; nt < 2; ++nt)
          acc[mt][nt] = __builtin_amdgcn_mfma_f32_32x32x16_bf16(af[mt], bfr[nt], acc[mt][nt], 0, 0, 0);
    }
    if (kc + 2 < 64) wait_vm_barrier_4();
    else             wait_vm_barrier_0();
    cur = (cur + 1 == 3) ? 0 : cur + 1;
  }

  // epilogue: divide by l, coalesced fp32 stores
  float* outb = out + (long)b * SEQ * DIM;
#pragma unroll
  for (int mt = 0; mt < 2; ++mt)
#pragma unroll
    for (int r = 0; r < 16; ++r) {
      const int row = r0 + mt * 32 + (r & 3) + 8 * (r >> 2) + 4 * half;
      const float inv = 1.0f / sl[row];
#pragma unroll
      for (int nt = 0; nt < 2; ++nt) {
        const int col = c0 + nt * 32 + ln;
        outb[(long)(i0 + row) * DIM + n0 + col] = acc[mt][nt][r] * inv;
      }
    }
}

extern "C" void kernel_launch(void* const* d_in, const int* in_sizes, int n_in,
                              void* d_out, int out_size, void* d_ws, size_t ws_size,
                              hipStream_t stream) {
  const float* x = (const float*)d_in[0];
  float* outp = (float*)d_out;

  unsigned short* xn = (unsigned short*)d_ws;                        // 16.78 MB
  unsigned short* xt = xn + (size_t)BATCH * SEQ * DIM;               // 16.78 MB (blocked)
  unsigned short* Pw = xt + (size_t)BATCH * SEQ * DIM;               // 67.1 MB
  float*          lw = (float*)(Pw + (size_t)BATCH * SEQ * SEQ);     // 64 KB

  hipMemsetAsync(lw, 0, (size_t)BATCH * SEQ * sizeof(float), stream);
  prep_kernel <<<BATCH * (SEQ / 32),  256, 0, stream>>>(x, xn, xt);
  gemm1_kernel<<<BATCH * 136,         256, 0, stream>>>(xn, Pw, lw);
  gemm2_kernel<<<BATCH * 16 * 4,      256, 0, stream>>>(Pw, xt, lw, outp);
}

// Round 8
// 159.916 us; speedup vs baseline: 1.0419x; 1.0419x over previous
//
#include <hip/hip_runtime.h>
#include <stdint.h>

#define BATCH 8
#define SEQ   2048
#define DIM   512

typedef __attribute__((ext_vector_type(8)))  short short8;    // 8 bf16 (4 VGPRs)
typedef __attribute__((ext_vector_type(16))) float floatx16;  // 32x32 C/D frag

static __device__ __forceinline__ unsigned short f32_bf16(float f) {
  unsigned u = __builtin_bit_cast(unsigned, f);
  u += 0x7FFFu + ((u >> 16) & 1u);          // round-to-nearest-even
  return (unsigned short)(u >> 16);
}
static __device__ __forceinline__ short8 ld_frag8(const unsigned short* p) {
  return __builtin_bit_cast(short8, *reinterpret_cast<const uint4*>(p));
}
static __device__ __forceinline__ void gld_lds16(const unsigned short* g, unsigned short* l) {
  __builtin_amdgcn_global_load_lds((const __attribute__((address_space(1))) unsigned int*)g,
                                   (__attribute__((address_space(3))) unsigned int*)l, 16, 0, 0);
}
static __device__ __forceinline__ float bf_lo(unsigned u) {
  return __builtin_bit_cast(float, u << 16);
}
static __device__ __forceinline__ float bf_hi(unsigned u) {
  return __builtin_bit_cast(float, u & 0xFFFF0000u);
}
static __device__ __forceinline__ float bfu(unsigned short u) {
  return __builtin_bit_cast(float, (unsigned)u << 16);
}
static __device__ __forceinline__ void wait_vm0_barrier() {
  asm volatile("s_waitcnt vmcnt(0)" ::: "memory");
  __builtin_amdgcn_s_barrier();
  __builtin_amdgcn_sched_barrier(0);
}
static __device__ __forceinline__ void wait_vm6_barrier() {
  asm volatile("s_waitcnt vmcnt(6)" ::: "memory");   // stage(kc+1) landed; kc+2 (6 loads) in flight
  __builtin_amdgcn_s_barrier();
  __builtin_amdgcn_sched_barrier(0);
}

// ---------------- prep: x -> xn (bf16 x-hat, row-major) and xt (bf16 x^T, BLOCKED) ---------
// xt layout: [b][jt][d][j&31]  (jt = j>>5) -> each block owns ONE contiguous 32KB chunk.
// grid 512 = 8 batches (XCD-pinned &7) x 64 j-tiles of 32 rows ; 256 threads
__global__ __launch_bounds__(256) void prep_kernel(const float* __restrict__ x,
                                                   unsigned short* __restrict__ xn,
                                                   unsigned short* __restrict__ xt) {
  const int b   = blockIdx.x & 7;
  const int jt  = blockIdx.x >> 3;     // 0..63
  const int t   = threadIdx.x;
  const int row = t >> 3;              // 0..31
  const int oct = t & 7;               // 0..7

  __shared__ unsigned short xs[512 * 34];   // [d][j] bf16, pitch 34 u16 (34.8 KB)

  const long rowg = ((long)b * SEQ + jt * 32 + row) * DIM;
  const float* xp = x + rowg;

  float4 v[16];
#pragma unroll
  for (int k = 0; k < 16; ++k)
    v[k] = *reinterpret_cast<const float4*>(xp + k * 32 + oct * 4);

  float acc = 0.f;
#pragma unroll
  for (int k = 0; k < 16; ++k)
    acc += v[k].x*v[k].x + v[k].y*v[k].y + v[k].z*v[k].z + v[k].w*v[k].w;
  acc += __shfl_xor(acc, 1);
  acc += __shfl_xor(acc, 2);
  acc += __shfl_xor(acc, 4);
  const float sc = 1.f / (sqrtf(acc) + 1e-12f);

  // xn straight from registers
  unsigned short* xnp = xn + rowg + oct * 4;
#pragma unroll
  for (int k = 0; k < 16; ++k) {
    ushort4 pk;
    pk.x = f32_bf16(v[k].x * sc); pk.y = f32_bf16(v[k].y * sc);
    pk.z = f32_bf16(v[k].z * sc); pk.w = f32_bf16(v[k].w * sc);
    *reinterpret_cast<ushort4*>(xnp + k * 32) = pk;
  }

  // LDS transpose staging: scalar u16 writes, bank = 4*oct + row/2 + const -> free
#pragma unroll
  for (int k = 0; k < 16; ++k) {
    const int d = k * 32 + oct * 4;
    xs[(d + 0) * 34 + row] = f32_bf16(v[k].x);
    xs[(d + 1) * 34 + row] = f32_bf16(v[k].y);
    xs[(d + 2) * 34 + row] = f32_bf16(v[k].z);
    xs[(d + 3) * 34 + row] = f32_bf16(v[k].w);
  }
  __syncthreads();

  // xt chunk store: contiguous 32KB, fully coalesced.
  unsigned short* xtb = xt + (size_t)(b * 64 + jt) * (512 * 32);
#pragma unroll
  for (int it = 0; it < 8; ++it) {
    const int a = t >> 2;                      // 0..63 d-sub
    const int q = (t & 3) ^ ((t >> 4) & 3);    // read/store group 0..3
    const int d = it * 64 + a;
    const unsigned* bp = reinterpret_cast<const unsigned*>(&xs[d * 34 + q * 8]);
    uint4 o;
    o.x = bp[0]; o.y = bp[1]; o.z = bp[2]; o.w = bp[3];
    *reinterpret_cast<uint4*>(xtb + d * 32 + q * 8) = o;
  }
}

// ---------------- gemm1 (symmetric, 2-phase prefetch, BK=64 — r5 proven): ----------------
// P[b,i,j] = bf16(exp(S^2-1)), upper-triangle tiles (grid 8 x 136).
// STAGE(kc+1) issued BEFORE compute(kc); raw s_barrier + asm vmcnt(0) once per kc.
// LDS 64KB dbuf (2 blk/CU). Mirror tile routed through LDS -> full-line stores.
__global__ __launch_bounds__(256, 2) void gemm1_kernel(const unsigned short* __restrict__ xn,
                                                       unsigned short* __restrict__ P,
                                                       float* __restrict__ lw) {
  const int b   = blockIdx.x & 7;
  int idx = blockIdx.x >> 3;           // 0..135 -> (ti, tj), ti <= tj
  int ti = 0;
#pragma unroll 1
  while (idx >= 16 - ti) { idx -= 16 - ti; ++ti; }
  const int tj = ti + idx;
  const int i0 = ti * 128;
  const int j0 = tj * 128;
  const bool diag = (ti == tj);

  const int tid  = threadIdx.x;
  const int w    = tid >> 6;
  const int lane = tid & 63;
  const int ln   = lane & 31;
  const int half = lane >> 5;

  // dbuf: buf k at k*16384 (A 8192 u16, B 8192 u16). sP (17408 u16) aliases buf0.
  __shared__ __align__(16) unsigned short smem[32768];   // 64 KB

  const unsigned short* xb = xn + (long)b * SEQ * DIM;
  const unsigned short* Ag = xb + (long)i0 * DIM;
  const unsigned short* Bg = xb + (long)j0 * DIM;

  floatx16 acc[2][2];
#pragma unroll
  for (int mt = 0; mt < 2; ++mt)
#pragma unroll
    for (int nt = 0; nt < 2; ++nt)
#pragma unroll
      for (int i = 0; i < 16; ++i) acc[mt][nt][i] = 0.f;

  const int r0 = (w >> 1) * 64;
  const int c0 = (w & 1) * 64;

  // ---- prologue: stage kc=0 into buf0 ----
  {
    unsigned short* bA = smem;
    unsigned short* bB = smem + 8192;
#pragma unroll
    for (int k = 0; k < 4; ++k) {
      int u = tid + k * 256;
      int row = u >> 3, c = u & 7;
      int gc = (c ^ ((row ^ (row >> 3)) & 7)) * 8;
      gld_lds16(Ag + (long)row * DIM + gc, bA + u * 8);
      if (!diag) gld_lds16(Bg + (long)row * DIM + gc, bB + u * 8);
    }
  }
  wait_vm0_barrier();

  for (int kc = 0; kc < 8; ++kc) {
    const int cur = kc & 1;
    if (kc < 7) {            // prefetch next chunk into the other buffer
      unsigned short* bA = smem + (cur ^ 1) * 16384;
      unsigned short* bB = bA + 8192;
      const int ko = (kc + 1) * 64;
#pragma unroll
      for (int k = 0; k < 4; ++k) {
        int u = tid + k * 256;
        int row = u >> 3, c = u & 7;
        int gc = (c ^ ((row ^ (row >> 3)) & 7)) * 8;
        gld_lds16(Ag + (long)row * DIM + ko + gc, bA + u * 8);
        if (!diag) gld_lds16(Bg + (long)row * DIM + ko + gc, bB + u * 8);
      }
      __builtin_amdgcn_sched_barrier(0);   // keep the issue cluster ahead of compute
    }
    unsigned short* cA = smem + cur * 16384;
    unsigned short* cB = diag ? cA : cA + 8192;
#pragma unroll
    for (int kk = 0; kk < 4; ++kk) {
      const int cc = kk * 2 + half;
      short8 af[2], bfr[2];
#pragma unroll
      for (int mt = 0; mt < 2; ++mt) {
        int r = r0 + mt * 32 + ln;
        af[mt] = ld_frag8(cA + r * 64 + ((cc ^ ((r ^ (r >> 3)) & 7)) * 8));
      }
#pragma unroll
      for (int nt = 0; nt < 2; ++nt) {
        int r = c0 + nt * 32 + ln;
        bfr[nt] = ld_frag8(cB + r * 64 + ((cc ^ ((r ^ (r >> 3)) & 7)) * 8));
      }
#pragma unroll
      for (int mt = 0; mt < 2; ++mt)
#pragma unroll
        for (int nt = 0; nt < 2; ++nt)
          acc[mt][nt] = __builtin_amdgcn_mfma_f32_32x32x16_bf16(af[mt], bfr[nt], acc[mt][nt], 0, 0, 0);
    }
    wait_vm0_barrier();      // prefetch landed during compute; buffers safe to swap
  }

  // epilogue: p = bf16(exp(s^2-1)) once into registers; feed sP, mirror, sums
  unsigned short pb[2][2][16];
  unsigned short* sP = smem;
#pragma unroll
  for (int mt = 0; mt < 2; ++mt)
#pragma unroll
    for (int nt = 0; nt < 2; ++nt) {
      const int col = c0 + nt * 32 + ln;
#pragma unroll
      for (int r = 0; r < 16; ++r) {
        float s = acc[mt][nt][r];
        unsigned short pv = f32_bf16(__expf(__builtin_fmaf(s, s, -1.0f)));
        pb[mt][nt][r] = pv;
        int row = r0 + mt * 32 + (r & 3) + 8 * (r >> 2) + 4 * half;
        sP[row * 136 + col] = pv;
      }
    }
  __syncthreads();

  unsigned short* Pg = P + (long)b * SEQ * SEQ;
  float* lwi = lw + b * SEQ + i0;
  float* lwj = lw + b * SEQ + j0;

  // tile (ti,tj): coalesced stores + fused row-sums
#pragma unroll
  for (int k = 0; k < 8; ++k) {
    int u = tid + k * 256;
    int row = u >> 4, c16 = u & 15;
    uint4 o = *reinterpret_cast<const uint4*>(sP + row * 136 + c16 * 8);
    *reinterpret_cast<uint4*>(Pg + (long)(i0 + row) * SEQ + j0 + c16 * 8) = o;
    float s = bf_lo(o.x) + bf_hi(o.x) + bf_lo(o.y) + bf_hi(o.y)
            + bf_lo(o.z) + bf_hi(o.z) + bf_lo(o.w) + bf_hi(o.w);
    s += __shfl_xor(s, 1);
    s += __shfl_xor(s, 2);
    s += __shfl_xor(s, 4);
    s += __shfl_xor(s, 8);
    if ((tid & 15) == 0) atomicAdd(&lwi[row], s);
  }

  if (!diag) {
    // column sums (= row sums of the mirror tile) from the exact bf16 register values
#pragma unroll
    for (int nt = 0; nt < 2; ++nt) {
      const int c = c0 + nt * 32 + ln;
      float s = 0.f;
#pragma unroll
      for (int mt = 0; mt < 2; ++mt)
#pragma unroll
        for (int r = 0; r < 16; ++r) s += bfu(pb[mt][nt][r]);
      s += __shfl_xor(s, 32);           // combine the two row-halves of this wave
      if (half == 0) atomicAdd(&lwj[c], s);
    }
    __syncthreads();                    // direct-tile reads of sP complete
    // rewrite sP TRANSPOSED (sP[c][i]) from registers, then store coalesced full lines
#pragma unroll
    for (int nt = 0; nt < 2; ++nt) {
      const int c = c0 + nt * 32 + ln;
#pragma unroll
      for (int mt = 0; mt < 2; ++mt)
#pragma unroll
        for (int r = 0; r < 16; ++r) {
          const int row = r0 + mt * 32 + (r & 3) + 8 * (r >> 2) + 4 * half;
          sP[c * 136 + row] = pb[mt][nt][r];
        }
    }
    __syncthreads();
#pragma unroll
    for (int k = 0; k < 8; ++k) {
      int u = tid + k * 256;
      int row = u >> 4, c16 = u & 15;   // row = mirror row (j-col), c16 over i
      uint4 o = *reinterpret_cast<const uint4*>(sP + row * 136 + c16 * 8);
      *reinterpret_cast<uint4*>(Pg + (long)(j0 + row) * SEQ + i0 + c16 * 8) = o;
    }
  }
}

// ---------------- gemm2 (256x128 tile, BK=64, 3-slot counted vmcnt): out = (P.x)/l --------
// grid 256 = 8 batches x 8 i-tiles(256) x 4 d-tiles(128), d-FAST ; 512 threads = 8 waves.
// LDS: 3 slots x (A 256x64 = 32KB + B 128x64 = 16KB) = 144KB -> 1 blk/CU.
// Stage = 6 loads/thread (4 A + 2 B). Loop: stage(kc+2) -> compute(kc) -> vmcnt(6)
// [stage(kc+1) landed; kc+2 in flight] -> s_barrier. Waits target loads issued TWO
// compute-phases (~700+cyc) ago; never drains in steady state. BK=64 keeps the proven
// conflict-free swizzle geometry (r7 lesson: BK=32's 64B pitch is structurally 4-way).
__global__ __launch_bounds__(512, 1) void gemm2_kernel(const unsigned short* __restrict__ P,
                                                       const unsigned short* __restrict__ xt,
                                                       const float* __restrict__ lw,
                                                       float* __restrict__ out) {
  const int b  = blockIdx.x & 7;
  const int t  = blockIdx.x >> 3;
  const int i0 = (t >> 2) * 256;       // d-fast: i0 slow
  const int n0 = (t & 3) * 128;        // d-fast: n0 fast
  const int tid  = threadIdx.x;
  const int w    = tid >> 6;           // 0..7
  const int lane = tid & 63;
  const int ln   = lane & 31;
  const int half = lane >> 5;

  // slot s at s*24576: A = 16384 u16 (256 rows x 64), B = 8192 u16 (128 rows x 64)
  __shared__ __align__(16) unsigned short smem[73728];   // 144 KB
  __shared__ float sl[256];

  const unsigned short* Ag = P  + (long)b * SEQ * SEQ + (long)i0 * SEQ;
  const unsigned short* Bg = xt + (size_t)b * DIM * SEQ;   // blocked chunks base

  if (tid < 256) sl[tid] = lw[b * SEQ + i0 + tid];

  floatx16 acc[2][2];
#pragma unroll
  for (int mt = 0; mt < 2; ++mt)
#pragma unroll
    for (int nt = 0; nt < 2; ++nt)
#pragma unroll
      for (int i = 0; i < 16; ++i) acc[mt][nt][i] = 0.f;

  const int r0 = (w >> 1) * 64;        // 0,64,128,192
  const int c0 = (w & 1) * 64;         // 0,64

  // stage slot s with K-chunk kc (BK=64): 4 A-loads + 2 B-loads per thread = 6
  auto stage = [&](int kc, int s) {
    unsigned short* bA = smem + s * 24576;
    unsigned short* bB = bA + 16384;
    const int ko = kc * 64;
#pragma unroll
    for (int k = 0; k < 4; ++k) {
      int u = tid + k * 512;                     // 0..2047 -> 256 rows x 8 granules
      int row = u >> 3, c = u & 7;
      int gc = (c ^ ((row ^ (row >> 3)) & 7)) * 8;
      gld_lds16(Ag + (long)row * SEQ + ko + gc, bA + u * 8);
    }
#pragma unroll
    for (int k = 0; k < 2; ++k) {
      int u = tid + k * 512;                     // 0..1023 -> 128 rows x 8 granules
      int row = u >> 3, c = u & 7;
      int sub = c ^ ((row ^ (row >> 3)) & 7);
      gld_lds16(Bg + ((size_t)(kc * 2 + (sub >> 2)) * 512 + n0 + row) * 32 + (sub & 3) * 8,
                bB + u * 8);
    }
  };

  stage(0, 0);
  stage(1, 1);
  wait_vm6_barrier();

  for (int kc = 0; kc < 32; ++kc) {
    if (kc + 2 < 32) {
      stage(kc + 2, (kc + 2) % 3);
      __builtin_amdgcn_sched_barrier(0);
    }
    unsigned short* cA = smem + (kc % 3) * 24576;
    unsigned short* cB = cA + 16384;
    __builtin_amdgcn_s_setprio(1);
#pragma unroll
    for (int kk = 0; kk < 4; ++kk) {
      const int cc = kk * 2 + half;
      short8 af[2], bfr[2];
#pragma unroll
      for (int mt = 0; mt < 2; ++mt) {
        int r = r0 + mt * 32 + ln;
        af[mt] = ld_frag8(cA + r * 64 + ((cc ^ ((r ^ (r >> 3)) & 7)) * 8));
      }
#pragma unroll
      for (int nt = 0; nt < 2; ++nt) {
        int r = c0 + nt * 32 + ln;
        bfr[nt] = ld_frag8(cB + r * 64 + ((cc ^ ((r ^ (r >> 3)) & 7)) * 8));
      }
#pragma unroll
      for (int mt = 0; mt < 2; ++mt)
#pragma unroll
        for (int nt = 0; nt < 2; ++nt)
          acc[mt][nt] = __builtin_amdgcn_mfma_f32_32x32x16_bf16(af[mt], bfr[nt], acc[mt][nt], 0, 0, 0);
    }
    __builtin_amdgcn_s_setprio(0);
    if (kc + 1 < 32) {
      if (kc + 2 < 32) wait_vm6_barrier();
      else             wait_vm0_barrier();
    }
  }

  // epilogue: divide by l, coalesced fp32 stores
  float* outb = out + (long)b * SEQ * DIM;
#pragma unroll
  for (int mt = 0; mt < 2; ++mt)
#pragma unroll
    for (int r = 0; r < 16; ++r) {
      const int row = r0 + mt * 32 + (r & 3) + 8 * (r >> 2) + 4 * half;
      const float inv = 1.0f / sl[row];
#pragma unroll
      for (int nt = 0; nt < 2; ++nt) {
        const int col = c0 + nt * 32 + ln;
        outb[(long)(i0 + row) * DIM + n0 + col] = acc[mt][nt][r] * inv;
      }
    }
}

extern "C" void kernel_launch(void* const* d_in, const int* in_sizes, int n_in,
                              void* d_out, int out_size, void* d_ws, size_t ws_size,
                              hipStream_t stream) {
  const float* x = (const float*)d_in[0];
  float* outp = (float*)d_out;

  unsigned short* xn = (unsigned short*)d_ws;                        // 16.78 MB
  unsigned short* xt = xn + (size_t)BATCH * SEQ * DIM;               // 16.78 MB (blocked)
  unsigned short* Pw = xt + (size_t)BATCH * SEQ * DIM;               // 67.1 MB
  float*          lw = (float*)(Pw + (size_t)BATCH * SEQ * SEQ);     // 64 KB

  hipMemsetAsync(lw, 0, (size_t)BATCH * SEQ * sizeof(float), stream);
  prep_kernel <<<BATCH * (SEQ / 32),  256, 0, stream>>>(x, xn, xt);
  gemm1_kernel<<<BATCH * 136,         256, 0, stream>>>(xn, Pw, lw);
  gemm2_kernel<<<BATCH * 8 * 4,       512, 0, stream>>>(Pw, xt, lw, outp);
}